// Round 14
// baseline (340.079 us; speedup 1.0000x reference)
//
#include <hip/hip_runtime.h>
#include <hip/hip_bf16.h>
#include <cstdint>
#include <cstddef>

#define DCH 128
#define NHEADS 2
#define NEG_SLOPE 0.2f

typedef __attribute__((ext_vector_type(8))) short short8v;
typedef __attribute__((ext_vector_type(4))) float f32x4;
typedef __attribute__((ext_vector_type(2))) float f32x2;
typedef _Float16 h4 __attribute__((ext_vector_type(4)));

// ---------------------------------------------------------------- utilities
__device__ __forceinline__ unsigned short f2bf(float f) {
    union { float f; unsigned int i; } v; v.f = f;
    unsigned int r = v.i + 0x7fffu + ((v.i >> 16) & 1u);   // RNE
    return (unsigned short)(r >> 16);
}
__device__ __forceinline__ unsigned short f2h_bits(float f) {
    _Float16 h = (_Float16)f;
    union { _Float16 h; unsigned short u; } v; v.h = h; return v.u;
}

// 32-lane-half sum via DPP row_ror + one ds_swizzle (xor16).
__device__ __forceinline__ float halfsum(float p) {
    p += __int_as_float(__builtin_amdgcn_update_dpp(
            0, __float_as_int(p), 0x121, 0xF, 0xF, false));  // row_ror:1
    p += __int_as_float(__builtin_amdgcn_update_dpp(
            0, __float_as_int(p), 0x122, 0xF, 0xF, false));  // row_ror:2
    p += __int_as_float(__builtin_amdgcn_update_dpp(
            0, __float_as_int(p), 0x124, 0xF, 0xF, false));  // row_ror:4
    p += __int_as_float(__builtin_amdgcn_update_dpp(
            0, __float_as_int(p), 0x128, 0xF, 0xF, false));  // row_ror:8
    p += __int_as_float(__builtin_amdgcn_ds_swizzle(
            __float_as_int(p), 0x401F));                     // lane ^= 16
    return p;
}

// ------------------------------- merged: weights->bf16 fragments + zero cnt
__global__ void prep_and_zero(const float* __restrict__ Wl, const float* __restrict__ Wr,
                              const float* __restrict__ resW,
                              unsigned short* __restrict__ wfrag,
                              int* __restrict__ cnt, int n) {
    if (blockIdx.x >= 40) {
        int i = (blockIdx.x - 40) * 256 + threadIdx.x;
        if (i < n) cnt[i] = 0;
        return;
    }
    int gid  = blockIdx.x * 256 + threadIdx.x;   // 10240 threads
    int lane = gid & 63;
    int f    = gid >> 6;                          // 0..159
    int ks   = f & 3;
    int ct   = f >> 2;
    int col  = ct * 16 + (lane & 15);
    int k0   = ks * 32 + (lane >> 4) * 8;
    const float* W; int ldB, c;
    if (col < 256)      { W = Wl;   ldB = 256; c = col; }
    else if (col < 512) { W = Wr;   ldB = 256; c = col - 256; }
    else                { W = resW; ldB = 128; c = col - 512; }
    unsigned short tmp[8];
#pragma unroll
    for (int j = 0; j < 8; ++j) tmp[j] = f2bf(W[(size_t)(k0 + j) * ldB + c]);
    ushort4* dst = (ushort4*)(wfrag + (size_t)gid * 8);
    dst[0] = make_ushort4(tmp[0], tmp[1], tmp[2], tmp[3]);
    dst[1] = make_ushort4(tmp[4], tmp[5], tmp[6], tmp[7]);
}

// ------- combined dispatch: blocks [0,3*nrb) = LN+MFMA GEMM (128-row tiles,
// section-split: sec 0 -> xl fp8, sec 1 -> xr f16, sec 2 -> out f32),
// blocks [3*nrb, ...) = fill_csr (int4, 4 edges/thread).
// GEMM outputs staged in 32KB LDS (aliases A tile), flushed full-line.
__launch_bounds__(256)
__global__ void gemm_fill(const float* __restrict__ x,
                          const float* __restrict__ gamma, const float* __restrict__ beta,
                          const unsigned short* __restrict__ wfrag,
                          const float* __restrict__ bl, const float* __restrict__ br,
                          const float* __restrict__ bias,
                          unsigned char* __restrict__ xl8, unsigned short* __restrict__ xr,
                          float* __restrict__ out, int n,
                          const int* __restrict__ srcIdx, const int* __restrict__ dstIdx,
                          int* __restrict__ fillc, int* __restrict__ sbuf, int E, int nrb) {
    __shared__ __align__(16) unsigned char smem[128 * 256];  // 32 KB (As / stage)

    if ((int)blockIdx.x >= 3 * nrb) {
        // ---------------- fill_csr part (4 edges per thread, int4 loads)
        int i = (blockIdx.x - 3 * nrb) * 256 + threadIdx.x;
        int E4 = E >> 2;
        if (i < E4) {
            int4 d = ((const int4*)dstIdx)[i];
            int4 s = ((const int4*)srcIdx)[i];
            sbuf[atomicAdd(&fillc[d.x], 1)] = s.x;
            sbuf[atomicAdd(&fillc[d.y], 1)] = s.y;
            sbuf[atomicAdd(&fillc[d.z], 1)] = s.z;
            sbuf[atomicAdd(&fillc[d.w], 1)] = s.w;
        }
        if (i < (E & 3)) {
            int e = E4 * 4 + i;
            sbuf[atomicAdd(&fillc[dstIdx[e]], 1)] = srcIdx[e];
        }
        return;
    }

    // ---------------- GEMM part (128 rows x one output section)
    int sec  = blockIdx.x / nrb;          // 0=xl, 1=xr, 2=out
    int rb   = blockIdx.x % nrb;
    int row0 = rb * 128;
    int tid  = threadIdx.x;
    unsigned short* As = (unsigned short*)smem;

    // stage A with fused LayerNorm+ReLU (bf16, XOR-swizzled), 16 passes
    {
        int r  = tid >> 5;            // 0..7
        int k4 = (tid & 31) * 4;      // 0,4,...,124
        float4 g4  = *(const float4*)(gamma + k4);
        float4 be4 = *(const float4*)(beta + k4);
#pragma unroll
        for (int i = 0; i < 16; ++i) {
            int row  = r + i * 8;
            int grow = row0 + row;
            float4 a = (grow < n) ? *(const float4*)(x + (size_t)grow * DCH + k4)
                                  : make_float4(0.f, 0.f, 0.f, 0.f);
            float s  = a.x + a.y + a.z + a.w;
            float sq = a.x * a.x + a.y * a.y + a.z * a.z + a.w * a.w;
#pragma unroll
            for (int msk = 16; msk; msk >>= 1) {
                s  += __shfl_xor(s, msk);
                sq += __shfl_xor(sq, msk);
            }
            float mu = s * (1.f / DCH);
            float rs = rsqrtf(sq * (1.f / DCH) - mu * mu + 1e-5f);
            ushort4 u;
            u.x = f2bf(fmaxf((a.x - mu) * rs * g4.x + be4.x, 0.f));
            u.y = f2bf(fmaxf((a.y - mu) * rs * g4.y + be4.y, 0.f));
            u.z = f2bf(fmaxf((a.z - mu) * rs * g4.z + be4.z, 0.f));
            u.w = f2bf(fmaxf((a.w - mu) * rs * g4.w + be4.w, 0.f));
            int byteoff = row * 256 + ((k4 * 2) ^ ((row & 7) << 4));
            *(ushort4*)((char*)As + byteoff) = u;
        }
    }
    __syncthreads();

    int wv = tid >> 6, lane = tid & 63;

    // A fragments: 2 row-groups x 4 K-slices per wave (32 rows/wave)
    short8v afrag[2][4];
#pragma unroll
    for (int g = 0; g < 2; ++g) {
        int arow = wv * 32 + g * 16 + (lane & 15);
#pragma unroll
        for (int ks = 0; ks < 4; ++ks) {
            int kbyte = (ks * 64 + (lane >> 4) * 16) ^ ((arow & 7) << 4);
            afrag[g][ks] = *(const short8v*)((const char*)As + arow * 256 + kbyte);
        }
    }
    __syncthreads();   // fragment reads done; smem becomes the stage buffer

    int nodeL0 = wv * 32 + (lane & 15);      // local node, group 0 (0..127)
    int nodeL1 = nodeL0 + 16;                // group 1
    int cq = (lane >> 4) << 2;               // column quad 0,4,8,12

    auto mfma_ct = [&](int ct, f32x4& a0, f32x4& a1) {
        const unsigned short* bp = wfrag + ((size_t)(ct * 4) * 64 + lane) * 8;
        short8v b0 = *(const short8v*)(bp);
        short8v b1 = *(const short8v*)(bp + 64 * 8);
        short8v b2 = *(const short8v*)(bp + 128 * 8);
        short8v b3 = *(const short8v*)(bp + 192 * 8);
        a0 = __builtin_amdgcn_mfma_f32_16x16x32_bf16(b0, afrag[0][0], a0, 0, 0, 0);
        a1 = __builtin_amdgcn_mfma_f32_16x16x32_bf16(b0, afrag[1][0], a1, 0, 0, 0);
        a0 = __builtin_amdgcn_mfma_f32_16x16x32_bf16(b1, afrag[0][1], a0, 0, 0, 0);
        a1 = __builtin_amdgcn_mfma_f32_16x16x32_bf16(b1, afrag[1][1], a1, 0, 0, 0);
        a0 = __builtin_amdgcn_mfma_f32_16x16x32_bf16(b2, afrag[0][2], a0, 0, 0, 0);
        a1 = __builtin_amdgcn_mfma_f32_16x16x32_bf16(b2, afrag[1][2], a1, 0, 0, 0);
        a0 = __builtin_amdgcn_mfma_f32_16x16x32_bf16(b3, afrag[0][3], a0, 0, 0, 0);
        a1 = __builtin_amdgcn_mfma_f32_16x16x32_bf16(b3, afrag[1][3], a1, 0, 0, 0);
    };

    if (sec == 0) {
        // ---- xl (fp8): 16 cts; stage = [128 nodes][256 B]
#pragma unroll
        for (int ct = 0; ct < 16; ++ct) {
            f32x4 a0 = {0,0,0,0}, a1 = {0,0,0,0};
            mfma_ct(ct, a0, a1);
            int c = ct * 16 + cq;
            float4 bb = *(const float4*)(bl + c);
            int cb = ct * 16 + cq;                       // byte in [0,256)
            int p0 = __builtin_amdgcn_cvt_pk_fp8_f32(a0[0] + bb.x, a0[1] + bb.y, 0, false);
            p0     = __builtin_amdgcn_cvt_pk_fp8_f32(a0[2] + bb.z, a0[3] + bb.w, p0, true);
            *(int*)(smem + nodeL0 * 256 + (cb ^ ((nodeL0 & 7) << 4))) = p0;
            int p1 = __builtin_amdgcn_cvt_pk_fp8_f32(a1[0] + bb.x, a1[1] + bb.y, 0, false);
            p1     = __builtin_amdgcn_cvt_pk_fp8_f32(a1[2] + bb.z, a1[3] + bb.w, p1, true);
            *(int*)(smem + nodeL1 * 256 + (cb ^ ((nodeL1 & 7) << 4))) = p1;
        }
        __syncthreads();
#pragma unroll
        for (int it = 0; it < 8; ++it) {        // flush 32KB, full-line stores
            int chunk = it * 256 + tid;
            int row  = chunk >> 4;
            int colb = (chunk & 15) * 16;
            int grow = row0 + row;
            if (grow < n) {
                int4 v = *(const int4*)(smem + row * 256 + (colb ^ ((row & 7) << 4)));
                *(int4*)(xl8 + (size_t)grow * 256 + colb) = v;
            }
        }
    } else if (sec == 1) {
        // ---- xr (f16): 2 flush-groups of 8 cts; stage = [128 nodes][128 col]
        for (int fg = 0; fg < 2; ++fg) {
#pragma unroll
            for (int ctl = 0; ctl < 8; ++ctl) {
                int ct = 16 + fg * 8 + ctl;
                f32x4 a0 = {0,0,0,0}, a1 = {0,0,0,0};
                mfma_ct(ct, a0, a1);
                int c = ct * 16 + cq - 256;              // col in [0,256)
                float4 bb = *(const float4*)(br + c);
                int cb = ctl * 32 + cq * 2;              // byte in [0,256)
                ushort4 u0 = make_ushort4(f2h_bits(a0[0] + bb.x), f2h_bits(a0[1] + bb.y),
                                          f2h_bits(a0[2] + bb.z), f2h_bits(a0[3] + bb.w));
                *(ushort4*)(smem + nodeL0 * 256 + (cb ^ ((nodeL0 & 7) << 4))) = u0;
                ushort4 u1 = make_ushort4(f2h_bits(a1[0] + bb.x), f2h_bits(a1[1] + bb.y),
                                          f2h_bits(a1[2] + bb.z), f2h_bits(a1[3] + bb.w));
                *(ushort4*)(smem + nodeL1 * 256 + (cb ^ ((nodeL1 & 7) << 4))) = u1;
            }
            __syncthreads();
#pragma unroll
            for (int it = 0; it < 8; ++it) {
                int chunk = it * 256 + tid;
                int row  = chunk >> 4;
                int colb = (chunk & 15) * 16;
                int grow = row0 + row;
                if (grow < n) {
                    int4 v = *(const int4*)(smem + row * 256 + (colb ^ ((row & 7) << 4)));
                    *(int4*)((char*)xr + (size_t)grow * 512 + fg * 256 + colb) = v;
                }
            }
            __syncthreads();
        }
    } else {
        // ---- out (f32): 2 flush-groups of 4 cts; stage = [128 rows][64 col]
        for (int fg = 0; fg < 2; ++fg) {
#pragma unroll
            for (int ctl = 0; ctl < 4; ++ctl) {
                int ct = 32 + fg * 4 + ctl;
                f32x4 a0 = {0,0,0,0}, a1 = {0,0,0,0};
                mfma_ct(ct, a0, a1);
                int c = ct * 16 + cq - 512;              // col in [0,128)
                float4 bb = *(const float4*)(bias + c);
                int cb = ctl * 64 + cq * 4;              // byte in [0,256)
                float4 w0 = make_float4(a0[0] + bb.x, a0[1] + bb.y,
                                        a0[2] + bb.z, a0[3] + bb.w);
                *(float4*)(smem + nodeL0 * 256 + (cb ^ ((nodeL0 & 7) << 4))) = w0;
                float4 w1 = make_float4(a1[0] + bb.x, a1[1] + bb.y,
                                        a1[2] + bb.z, a1[3] + bb.w);
                *(float4*)(smem + nodeL1 * 256 + (cb ^ ((nodeL1 & 7) << 4))) = w1;
            }
            __syncthreads();
#pragma unroll
            for (int it = 0; it < 8; ++it) {    // flush + residual x
                int chunk = it * 256 + tid;
                int row  = chunk >> 4;
                int colb = (chunk & 15) * 16;
                int grow = row0 + row;
                if (grow < n) {
                    float4 v = *(const float4*)(smem + row * 256 + (colb ^ ((row & 7) << 4)));
                    float4 xv = *(const float4*)((const char*)x + (size_t)grow * 512 + fg * 256 + colb);
                    v.x += xv.x; v.y += xv.y; v.z += xv.z; v.w += xv.w;
                    *(float4*)((char*)out + (size_t)grow * 512 + fg * 256 + colb) = v;
                }
            }
            __syncthreads();
        }
    }
}

// --------------------------------------------------------------- CSR build
__global__ void hist_dst(const int* __restrict__ dst, int* __restrict__ cnt, int E) {
    int i = blockIdx.x * blockDim.x + threadIdx.x;
    int E4 = E >> 2;
    if (i < E4) {
        int4 d = ((const int4*)dst)[i];
        atomicAdd(&cnt[d.x], 1); atomicAdd(&cnt[d.y], 1);
        atomicAdd(&cnt[d.z], 1); atomicAdd(&cnt[d.w], 1);
    }
    if (i < (E & 3)) atomicAdd(&cnt[dst[E4 * 4 + i]], 1);
}

__global__ void scan_block(const int* __restrict__ cnt, int* __restrict__ offs,
                           int* __restrict__ bsum, int n) {
    __shared__ int sm[256];
    int t = threadIdx.x;
    int i = blockIdx.x * 256 + t;
    int v = (i < n) ? cnt[i] : 0;
    sm[t] = v;
    __syncthreads();
#pragma unroll
    for (int d = 1; d < 256; d <<= 1) {
        int add = (t >= d) ? sm[t - d] : 0;
        __syncthreads();
        sm[t] += add;
        __syncthreads();
    }
    if (i < n) offs[i] = sm[t] - v;
    if (t == 255) bsum[blockIdx.x] = sm[t];
}

__global__ void scan_bsum_par(int* __restrict__ bsum, int nb) {
    __shared__ int sm[512];
    int t = threadIdx.x;
    if (nb <= 512) {
        int v = (t < nb) ? bsum[t] : 0;
        sm[t] = v;
        __syncthreads();
#pragma unroll
        for (int d = 1; d < 512; d <<= 1) {
            int add = (t >= d) ? sm[t - d] : 0;
            __syncthreads();
            sm[t] += add;
            __syncthreads();
        }
        if (t < nb) bsum[t] = sm[t] - v;
    } else if (t == 0) {
        int acc = 0;
        for (int i = 0; i < nb; ++i) { int v = bsum[i]; bsum[i] = acc; acc += v; }
    }
}

__global__ void scan_add(int* __restrict__ offs, int* __restrict__ fillc,
                         const int* __restrict__ bsum, int n, int E) {
    int i = blockIdx.x * 256 + threadIdx.x;
    if (i < n) {
        int v = offs[i] + bsum[blockIdx.x];
        offs[i]  = v;
        fillc[i] = v;
    }
    if (i == 0) offs[n] = E;
}

// --------------- single-pass fused attention + softmax + aggregation (fp8)
// One wave per dst node t; fp8 xl gathers (256 B/edge); lane-local per-head
// online (m,z) + defer-max; software-pipelined 4-edge groups.
__launch_bounds__(256)
__global__ void gat_aggregate(const int* __restrict__ offs, const int* __restrict__ sbuf,
                              const unsigned char* __restrict__ xl8,
                              const unsigned short* __restrict__ xr_,
                              const float* __restrict__ att,
                              float* __restrict__ out, int n) {
    const _Float16* xr = (const _Float16*)xr_;
    int lane = threadIdx.x & 63;
    int wid  = __builtin_amdgcn_readfirstlane((blockIdx.x * blockDim.x + threadIdx.x) >> 6);
    int nw   = (gridDim.x * blockDim.x) >> 6;

    const float LOG2E = 1.4426950408889634f;
    float4 af = *(const float4*)(att + lane * 4);   // flat[256]: lanes 0..31 head0
    float ax = af.x * LOG2E, ay = af.y * LOG2E, az = af.z * LOG2E, aw = af.w * LOG2E;

    for (int t = wid; t < n; t += nw) {
        int beg = offs[t];
        int end = offs[t + 1];
        if (beg == end) continue;
        h4 rr = *(const h4*)(xr + (size_t)t * 256 + lane * 4);
        float rx = (float)rr[0], ry = (float)rr[1], rz = (float)rr[2], rw = (float)rr[3];

        float m = -INFINITY, z = 0.f;
        float4 acc = make_float4(0.f, 0.f, 0.f, 0.f);

        auto process4 = [&](int u0, int u1, int u2, int u3) {
            f32x2 l0a = __builtin_amdgcn_cvt_pk_f32_fp8(u0, false);
            f32x2 l0b = __builtin_amdgcn_cvt_pk_f32_fp8(u0, true);
            f32x2 l1a = __builtin_amdgcn_cvt_pk_f32_fp8(u1, false);
            f32x2 l1b = __builtin_amdgcn_cvt_pk_f32_fp8(u1, true);
            f32x2 l2a = __builtin_amdgcn_cvt_pk_f32_fp8(u2, false);
            f32x2 l2b = __builtin_amdgcn_cvt_pk_f32_fp8(u2, true);
            f32x2 l3a = __builtin_amdgcn_cvt_pk_f32_fp8(u3, false);
            f32x2 l3b = __builtin_amdgcn_cvt_pk_f32_fp8(u3, true);

            auto logit = [&](f32x2 la, f32x2 lb) {
                float vx = la.x + rx; vx = fmaxf(vx, NEG_SLOPE * vx);
                float vy = la.y + ry; vy = fmaxf(vy, NEG_SLOPE * vy);
                float vz = lb.x + rz; vz = fmaxf(vz, NEG_SLOPE * vz);
                float vw = lb.y + rw; vw = fmaxf(vw, NEG_SLOPE * vw);
                return fmaf(vw, aw, fmaf(vz, az, fmaf(vy, ay, vx * ax)));
            };
            float p0 = halfsum(logit(l0a, l0b));
            float p1 = halfsum(logit(l1a, l1b));
            float p2 = halfsum(logit(l2a, l2b));
            float p3 = halfsum(logit(l3a, l3b));
            float pm = fmaxf(fmaxf(p0, p1), fmaxf(p2, p3));
            if (__any(pm - m > 11.5f)) {
                float mn = fmaxf(m, pm);
                float sc = __builtin_amdgcn_exp2f(m - mn);   // 0 on first group
                z *= sc;
                acc.x *= sc; acc.y *= sc; acc.z *= sc; acc.w *= sc;
                m = mn;
            }
            float w0 = __builtin_amdgcn_exp2f(p0 - m);
            float w1 = __builtin_amdgcn_exp2f(p1 - m);
            float w2 = __builtin_amdgcn_exp2f(p2 - m);
            float w3 = __builtin_amdgcn_exp2f(p3 - m);
            z += (w0 + w1) + (w2 + w3);
            acc.x = fmaf(l0a.x, w0, acc.x); acc.y = fmaf(l0a.y, w0, acc.y);
            acc.z = fmaf(l0b.x, w0, acc.z); acc.w = fmaf(l0b.y, w0, acc.w);
            acc.x = fmaf(l1a.x, w1, acc.x); acc.y = fmaf(l1a.y, w1, acc.y);
            acc.z = fmaf(l1b.x, w1, acc.z); acc.w = fmaf(l1b.y, w1, acc.w);
            acc.x = fmaf(l2a.x, w2, acc.x); acc.y = fmaf(l2a.y, w2, acc.y);
            acc.z = fmaf(l2b.x, w2, acc.z); acc.w = fmaf(l2b.y, w2, acc.w);
            acc.x = fmaf(l3a.x, w3, acc.x); acc.y = fmaf(l3a.y, w3, acc.y);
            acc.z = fmaf(l3b.x, w3, acc.z); acc.w = fmaf(l3b.y, w3, acc.w);
        };

        int j = beg;
        int c0, c1, c2, c3;
        bool have = (j + 4 <= end);
        if (have) {
            int s0 = sbuf[j], s1 = sbuf[j + 1], s2 = sbuf[j + 2], s3 = sbuf[j + 3];
            c0 = *(const int*)(xl8 + (size_t)s0 * 256 + lane * 4);
            c1 = *(const int*)(xl8 + (size_t)s1 * 256 + lane * 4);
            c2 = *(const int*)(xl8 + (size_t)s2 * 256 + lane * 4);
            c3 = *(const int*)(xl8 + (size_t)s3 * 256 + lane * 4);
        }
        for (; j + 8 <= end; j += 4) {
            int s0 = sbuf[j + 4], s1 = sbuf[j + 5], s2 = sbuf[j + 6], s3 = sbuf[j + 7];
            int n0 = *(const int*)(xl8 + (size_t)s0 * 256 + lane * 4);
            int n1 = *(const int*)(xl8 + (size_t)s1 * 256 + lane * 4);
            int n2 = *(const int*)(xl8 + (size_t)s2 * 256 + lane * 4);
            int n3 = *(const int*)(xl8 + (size_t)s3 * 256 + lane * 4);
            process4(c0, c1, c2, c3);
            c0 = n0; c1 = n1; c2 = n2; c3 = n3;
        }
        if (have) { process4(c0, c1, c2, c3); j += 4; }
        for (; j < end; ++j) {                   // tail (0..3 edges)
            int u = *(const int*)(xl8 + (size_t)sbuf[j] * 256 + lane * 4);
            f32x2 la = __builtin_amdgcn_cvt_pk_f32_fp8(u, false);
            f32x2 lb = __builtin_amdgcn_cvt_pk_f32_fp8(u, true);
            float vx = la.x + rx; vx = fmaxf(vx, NEG_SLOPE * vx);
            float vy = la.y + ry; vy = fmaxf(vy, NEG_SLOPE * vy);
            float vz = lb.x + rz; vz = fmaxf(vz, NEG_SLOPE * vz);
            float vw = lb.y + rw; vw = fmaxf(vw, NEG_SLOPE * vw);
            float p = halfsum(fmaf(vw, aw, fmaf(vz, az, fmaf(vy, ay, vx * ax))));
            if (__any(p - m > 11.5f)) {
                float mn = fmaxf(m, p);
                float sc = __builtin_amdgcn_exp2f(m - mn);
                z *= sc;
                acc.x *= sc; acc.y *= sc; acc.z *= sc; acc.w *= sc;
                m = mn;
            }
            float w = __builtin_amdgcn_exp2f(p - m);
            z += w;
            acc.x = fmaf(la.x, w, acc.x); acc.y = fmaf(la.y, w, acc.y);
            acc.z = fmaf(lb.x, w, acc.z); acc.w = fmaf(lb.y, w, acc.w);
        }
        float inv = 0.5f / (z + 1e-16f);         // z uniform within each half
        acc.x *= inv; acc.y *= inv; acc.z *= inv; acc.w *= inv;
        // head mean: lane L (<32) += lane L+32 (same channels, head 1)
        acc.x += __shfl_xor(acc.x, 32);
        acc.y += __shfl_xor(acc.y, 32);
        acc.z += __shfl_xor(acc.z, 32);
        acc.w += __shfl_xor(acc.w, 32);
        if (lane < 32) {
            float4* o = (float4*)(out + (size_t)t * DCH + lane * 4);
            float4 cur = *o;
            cur.x += acc.x; cur.y += acc.y; cur.z += acc.z; cur.w += acc.w;
            *o = cur;
        }
    }
}

// --------------------------------------------------------------------- launch
extern "C" void kernel_launch(void* const* d_in, const int* in_sizes, int n_in,
                              void* d_out, int out_size, void* d_ws, size_t ws_size,
                              hipStream_t stream) {
    const float* x     = (const float*)d_in[0];
    const int*   ei    = (const int*)d_in[1];
    const float* gamma = (const float*)d_in[2];
    const float* beta  = (const float*)d_in[3];
    const float* Wl    = (const float*)d_in[4];
    const float* bl    = (const float*)d_in[5];
    const float* Wr    = (const float*)d_in[6];
    const float* br    = (const float*)d_in[7];
    const float* att   = (const float*)d_in[8];
    const float* resW  = (const float*)d_in[9];
    const float* bias  = (const float*)d_in[10];
    float* out = (float*)d_out;

    int n = in_sizes[0] / DCH;
    int E = in_sizes[1] / 2;
    const int* src = ei;
    const int* dstIdx = ei + E;

    char* ws = (char*)d_ws;
    size_t off = 0;
    auto alloc = [&](size_t bytes) -> void* {
        void* p = ws + off;
        off = (off + bytes + 255) & ~(size_t)255;
        return p;
    };

    int nb = (n + 255) / 256;

    unsigned char*  xl8 = (unsigned char*)alloc((size_t)n * 256);       // 25.6 MB
    unsigned short* xr  = (unsigned short*)alloc((size_t)n * 256 * 2);  // 51.2 MB
    unsigned short* wfrag = (unsigned short*)alloc(160 * 64 * 8 * 2);   // 160 KB
    int* cnt   = (int*)alloc((size_t)n * 4);
    int* offs  = (int*)alloc((size_t)(n + 1) * 4);
    int* bsum  = (int*)alloc((size_t)nb * 4);
    int* fillc = (int*)alloc((size_t)n * 4);
    int* sbuf  = (int*)alloc((size_t)E * 4);                            // 6.4 MB

    prep_and_zero<<<40 + nb, 256, 0, stream>>>(Wl, Wr, resW, wfrag, cnt, n);
    int ethr = (E / 4 + 255) / 256 + 1;
    hist_dst<<<ethr, 256, 0, stream>>>(dstIdx, cnt, E);
    scan_block<<<nb, 256, 0, stream>>>(cnt, offs, bsum, n);
    scan_bsum_par<<<1, 512, 0, stream>>>(bsum, nb);
    scan_add<<<nb, 256, 0, stream>>>(offs, fillc, bsum, n, E);

    int nrb = (n + 127) / 128;
    gemm_fill<<<3 * nrb + ethr, 256, 0, stream>>>(x, gamma, beta, wfrag, bl, br, bias,
                                                  xl8, xr, out, n,
                                                  src, dstIdx, fillc, sbuf, E, nrb);
    gat_aggregate<<<2048, 256, 0, stream>>>(offs, sbuf, xl8, xr, att, out, n);
}

// Round 16
// 294.003 us; speedup vs baseline: 1.1567x; 1.1567x over previous
//
#include <hip/hip_runtime.h>
#include <hip/hip_bf16.h>
#include <cstdint>
#include <cstddef>

#define DCH 128
#define NHEADS 2
#define NEG_SLOPE 0.2f

typedef __attribute__((ext_vector_type(8))) short short8v;
typedef __attribute__((ext_vector_type(4))) float f32x4;
typedef __attribute__((ext_vector_type(2))) float f32x2;
typedef __attribute__((ext_vector_type(4))) int int4v;
typedef _Float16 h4 __attribute__((ext_vector_type(4)));

// ---------------------------------------------------------------- utilities
__device__ __forceinline__ unsigned short f2bf(float f) {
    union { float f; unsigned int i; } v; v.f = f;
    unsigned int r = v.i + 0x7fffu + ((v.i >> 16) & 1u);   // RNE
    return (unsigned short)(r >> 16);
}
__device__ __forceinline__ unsigned short f2h_bits(float f) {
    _Float16 h = (_Float16)f;
    union { _Float16 h; unsigned short u; } v; v.h = h; return v.u;
}

// 32-lane-half sum via DPP row_ror + one ds_swizzle (xor16).
__device__ __forceinline__ float halfsum(float p) {
    p += __int_as_float(__builtin_amdgcn_update_dpp(
            0, __float_as_int(p), 0x121, 0xF, 0xF, false));  // row_ror:1
    p += __int_as_float(__builtin_amdgcn_update_dpp(
            0, __float_as_int(p), 0x122, 0xF, 0xF, false));  // row_ror:2
    p += __int_as_float(__builtin_amdgcn_update_dpp(
            0, __float_as_int(p), 0x124, 0xF, 0xF, false));  // row_ror:4
    p += __int_as_float(__builtin_amdgcn_update_dpp(
            0, __float_as_int(p), 0x128, 0xF, 0xF, false));  // row_ror:8
    p += __int_as_float(__builtin_amdgcn_ds_swizzle(
            __float_as_int(p), 0x401F));                     // lane ^= 16
    return p;
}

// ------------- merged: weights->bf16 fragments + dst histogram (cnt pre-zeroed
// by hipMemsetAsync). Blocks [0,40): wfrag; blocks >= 40: int4 histogram.
__global__ void prep_hist(const float* __restrict__ Wl, const float* __restrict__ Wr,
                          const float* __restrict__ resW,
                          unsigned short* __restrict__ wfrag,
                          const int* __restrict__ dst, int* __restrict__ cnt, int E) {
    if (blockIdx.x >= 40) {
        int i = (blockIdx.x - 40) * 256 + threadIdx.x;
        int E4 = E >> 2;
        if (i < E4) {
            int4 d = ((const int4*)dst)[i];
            atomicAdd(&cnt[d.x], 1); atomicAdd(&cnt[d.y], 1);
            atomicAdd(&cnt[d.z], 1); atomicAdd(&cnt[d.w], 1);
        }
        if (i < (E & 3)) atomicAdd(&cnt[dst[E4 * 4 + i]], 1);
        return;
    }
    int gid  = blockIdx.x * 256 + threadIdx.x;   // 10240 threads
    int lane = gid & 63;
    int f    = gid >> 6;                          // 0..159
    int ks   = f & 3;
    int ct   = f >> 2;
    int col  = ct * 16 + (lane & 15);
    int k0   = ks * 32 + (lane >> 4) * 8;
    const float* W; int ldB, c;
    if (col < 256)      { W = Wl;   ldB = 256; c = col; }
    else if (col < 512) { W = Wr;   ldB = 256; c = col - 256; }
    else                { W = resW; ldB = 128; c = col - 512; }
    unsigned short tmp[8];
#pragma unroll
    for (int j = 0; j < 8; ++j) tmp[j] = f2bf(W[(size_t)(k0 + j) * ldB + c]);
    ushort4* dstp = (ushort4*)(wfrag + (size_t)gid * 8);
    dstp[0] = make_ushort4(tmp[0], tmp[1], tmp[2], tmp[3]);
    dstp[1] = make_ushort4(tmp[4], tmp[5], tmp[6], tmp[7]);
}

// ------- combined dispatch: blocks [0,nrb) = LN+MFMA GEMM (128-row tiles),
// rest = fill_csr (int4, 4 edges/thread).
// GEMM outputs staged in 32KB LDS (aliases A tile), flushed full-line.
// xl fp8 (normal stores -> stays in L2 for gat); xr f16 and out f32 flushed
// NONTEMPORAL (read-once-later streams; keeps L2 free for sbuf + xl8).
__launch_bounds__(256)
__global__ void gemm_fill(const float* __restrict__ x,
                          const float* __restrict__ gamma, const float* __restrict__ beta,
                          const unsigned short* __restrict__ wfrag,
                          const float* __restrict__ bl, const float* __restrict__ br,
                          const float* __restrict__ bias,
                          unsigned char* __restrict__ xl8, unsigned short* __restrict__ xr,
                          float* __restrict__ out, int n,
                          const int* __restrict__ srcIdx, const int* __restrict__ dstIdx,
                          int* __restrict__ fillc, int* __restrict__ sbuf, int E, int nrb) {
    __shared__ __align__(16) unsigned char smem[128 * 256];  // 32 KB (As / stage)

    if ((int)blockIdx.x >= nrb) {
        // ---------------- fill_csr part (4 edges per thread, int4 loads)
        int i = (blockIdx.x - nrb) * 256 + threadIdx.x;
        int E4 = E >> 2;
        if (i < E4) {
            int4 d = ((const int4*)dstIdx)[i];
            int4 s = ((const int4*)srcIdx)[i];
            sbuf[atomicAdd(&fillc[d.x], 1)] = s.x;
            sbuf[atomicAdd(&fillc[d.y], 1)] = s.y;
            sbuf[atomicAdd(&fillc[d.z], 1)] = s.z;
            sbuf[atomicAdd(&fillc[d.w], 1)] = s.w;
        }
        if (i < (E & 3)) {
            int e = E4 * 4 + i;
            sbuf[atomicAdd(&fillc[dstIdx[e]], 1)] = srcIdx[e];
        }
        return;
    }

    // ---------------- GEMM part (128 rows x 640 cols)
    int row0 = blockIdx.x * 128;
    int tid  = threadIdx.x;
    unsigned short* As = (unsigned short*)smem;

    // stage A with fused LayerNorm+ReLU (bf16, XOR-swizzled)
    {
        int r  = tid >> 5;            // 0..7
        int k4 = (tid & 31) * 4;      // 0,4,...,124
        float4 g4  = *(const float4*)(gamma + k4);
        float4 be4 = *(const float4*)(beta + k4);
#pragma unroll
        for (int i = 0; i < 16; ++i) {
            int row  = r + i * 8;
            int grow = row0 + row;
            float4 a = (grow < n) ? *(const float4*)(x + (size_t)grow * DCH + k4)
                                  : make_float4(0.f, 0.f, 0.f, 0.f);
            float s  = a.x + a.y + a.z + a.w;
            float sq = a.x * a.x + a.y * a.y + a.z * a.z + a.w * a.w;
#pragma unroll
            for (int msk = 16; msk; msk >>= 1) {
                s  += __shfl_xor(s, msk);
                sq += __shfl_xor(sq, msk);
            }
            float mu = s * (1.f / DCH);
            float rs = rsqrtf(sq * (1.f / DCH) - mu * mu + 1e-5f);
            ushort4 u;
            u.x = f2bf(fmaxf((a.x - mu) * rs * g4.x + be4.x, 0.f));
            u.y = f2bf(fmaxf((a.y - mu) * rs * g4.y + be4.y, 0.f));
            u.z = f2bf(fmaxf((a.z - mu) * rs * g4.z + be4.z, 0.f));
            u.w = f2bf(fmaxf((a.w - mu) * rs * g4.w + be4.w, 0.f));
            int byteoff = row * 256 + ((k4 * 2) ^ ((row & 7) << 4));
            *(ushort4*)((char*)As + byteoff) = u;
        }
    }
    __syncthreads();

    int wv = tid >> 6, lane = tid & 63;

    short8v afrag[2][4];
#pragma unroll
    for (int g = 0; g < 2; ++g) {
        int arow = wv * 32 + g * 16 + (lane & 15);
#pragma unroll
        for (int ks = 0; ks < 4; ++ks) {
            int kbyte = (ks * 64 + (lane >> 4) * 16) ^ ((arow & 7) << 4);
            afrag[g][ks] = *(const short8v*)((const char*)As + arow * 256 + kbyte);
        }
    }
    __syncthreads();   // fragment reads done; smem becomes the stage buffer

    int nodeL0 = wv * 32 + (lane & 15);      // local node, group 0 (0..127)
    int nodeL1 = nodeL0 + 16;                // group 1
    int cq = (lane >> 4) << 2;               // column quad 0,4,8,12

    auto mfma_ct = [&](int ct, f32x4& a0, f32x4& a1) {
        const unsigned short* bp = wfrag + ((size_t)(ct * 4) * 64 + lane) * 8;
        short8v b0 = *(const short8v*)(bp);
        short8v b1 = *(const short8v*)(bp + 64 * 8);
        short8v b2 = *(const short8v*)(bp + 128 * 8);
        short8v b3 = *(const short8v*)(bp + 192 * 8);
        a0 = __builtin_amdgcn_mfma_f32_16x16x32_bf16(b0, afrag[0][0], a0, 0, 0, 0);
        a1 = __builtin_amdgcn_mfma_f32_16x16x32_bf16(b0, afrag[1][0], a1, 0, 0, 0);
        a0 = __builtin_amdgcn_mfma_f32_16x16x32_bf16(b1, afrag[0][1], a0, 0, 0, 0);
        a1 = __builtin_amdgcn_mfma_f32_16x16x32_bf16(b1, afrag[1][1], a1, 0, 0, 0);
        a0 = __builtin_amdgcn_mfma_f32_16x16x32_bf16(b2, afrag[0][2], a0, 0, 0, 0);
        a1 = __builtin_amdgcn_mfma_f32_16x16x32_bf16(b2, afrag[1][2], a1, 0, 0, 0);
        a0 = __builtin_amdgcn_mfma_f32_16x16x32_bf16(b3, afrag[0][3], a0, 0, 0, 0);
        a1 = __builtin_amdgcn_mfma_f32_16x16x32_bf16(b3, afrag[1][3], a1, 0, 0, 0);
    };

    // ---- xl (fp8): 16 cts; stage = [128 nodes][256 B]; NORMAL stores
    {
#pragma unroll
        for (int ct = 0; ct < 16; ++ct) {
            f32x4 a0 = {0,0,0,0}, a1 = {0,0,0,0};
            mfma_ct(ct, a0, a1);
            int c = ct * 16 + cq;
            float4 bb = *(const float4*)(bl + c);
            int cb = ct * 16 + cq;                       // byte in [0,256)
            int p0 = __builtin_amdgcn_cvt_pk_fp8_f32(a0[0] + bb.x, a0[1] + bb.y, 0, false);
            p0     = __builtin_amdgcn_cvt_pk_fp8_f32(a0[2] + bb.z, a0[3] + bb.w, p0, true);
            *(int*)(smem + nodeL0 * 256 + (cb ^ ((nodeL0 & 7) << 4))) = p0;
            int p1 = __builtin_amdgcn_cvt_pk_fp8_f32(a1[0] + bb.x, a1[1] + bb.y, 0, false);
            p1     = __builtin_amdgcn_cvt_pk_fp8_f32(a1[2] + bb.z, a1[3] + bb.w, p1, true);
            *(int*)(smem + nodeL1 * 256 + (cb ^ ((nodeL1 & 7) << 4))) = p1;
        }
        __syncthreads();
#pragma unroll
        for (int it = 0; it < 8; ++it) {        // flush 32KB, full-line stores
            int chunk = it * 256 + tid;
            int row  = chunk >> 4;
            int colb = (chunk & 15) * 16;
            int grow = row0 + row;
            if (grow < n) {
                int4v v = *(const int4v*)(smem + row * 256 + (colb ^ ((row & 7) << 4)));
                *(int4v*)(xl8 + (size_t)grow * 256 + colb) = v;
            }
        }
        __syncthreads();
    }

    // ---- xr (f16): 2 flush-groups of 8 cts; NONTEMPORAL flush
    for (int fg = 0; fg < 2; ++fg) {
#pragma unroll
        for (int ctl = 0; ctl < 8; ++ctl) {
            int ct = 16 + fg * 8 + ctl;
            f32x4 a0 = {0,0,0,0}, a1 = {0,0,0,0};
            mfma_ct(ct, a0, a1);
            int c = ct * 16 + cq - 256;                  // col in [0,256)
            float4 bb = *(const float4*)(br + c);
            int cb = ctl * 32 + cq * 2;                  // byte in [0,256)
            ushort4 u0 = make_ushort4(f2h_bits(a0[0] + bb.x), f2h_bits(a0[1] + bb.y),
                                      f2h_bits(a0[2] + bb.z), f2h_bits(a0[3] + bb.w));
            *(ushort4*)(smem + nodeL0 * 256 + (cb ^ ((nodeL0 & 7) << 4))) = u0;
            ushort4 u1 = make_ushort4(f2h_bits(a1[0] + bb.x), f2h_bits(a1[1] + bb.y),
                                      f2h_bits(a1[2] + bb.z), f2h_bits(a1[3] + bb.w));
            *(ushort4*)(smem + nodeL1 * 256 + (cb ^ ((nodeL1 & 7) << 4))) = u1;
        }
        __syncthreads();
#pragma unroll
        for (int it = 0; it < 8; ++it) {
            int chunk = it * 256 + tid;
            int row  = chunk >> 4;
            int colb = (chunk & 15) * 16;
            int grow = row0 + row;
            if (grow < n) {
                int4v v = *(const int4v*)(smem + row * 256 + (colb ^ ((row & 7) << 4)));
                __builtin_nontemporal_store(v,
                    (int4v*)((char*)xr + (size_t)grow * 512 + fg * 256 + colb));
            }
        }
        __syncthreads();
    }

    // ---- out: 2 flush-groups of 4 cts; NONTEMPORAL flush + residual x
    for (int fg = 0; fg < 2; ++fg) {
#pragma unroll
        for (int ctl = 0; ctl < 4; ++ctl) {
            int ct = 32 + fg * 4 + ctl;
            f32x4 a0 = {0,0,0,0}, a1 = {0,0,0,0};
            mfma_ct(ct, a0, a1);
            int c = ct * 16 + cq - 512;                  // col in [0,128)
            float4 bb = *(const float4*)(bias + c);
            int cb = ctl * 64 + cq * 4;                  // byte in [0,256)
            float4 w0 = make_float4(a0[0] + bb.x, a0[1] + bb.y,
                                    a0[2] + bb.z, a0[3] + bb.w);
            *(float4*)(smem + nodeL0 * 256 + (cb ^ ((nodeL0 & 7) << 4))) = w0;
            float4 w1 = make_float4(a1[0] + bb.x, a1[1] + bb.y,
                                    a1[2] + bb.z, a1[3] + bb.w);
            *(float4*)(smem + nodeL1 * 256 + (cb ^ ((nodeL1 & 7) << 4))) = w1;
        }
        __syncthreads();
#pragma unroll
        for (int it = 0; it < 8; ++it) {
            int chunk = it * 256 + tid;
            int row  = chunk >> 4;
            int colb = (chunk & 15) * 16;
            int grow = row0 + row;
            if (grow < n) {
                f32x4 v = *(const f32x4*)(smem + row * 256 + (colb ^ ((row & 7) << 4)));
                const float* xp = (const float*)((const char*)x + (size_t)grow * 512 + fg * 256 + colb);
                f32x4 xv = *(const f32x4*)xp;
                v = v + xv;
                __builtin_nontemporal_store(v,
                    (f32x4*)((char*)out + (size_t)grow * 512 + fg * 256 + colb));
            }
        }
        __syncthreads();
    }
}

// --------------------------------------------------------------- CSR scans
__global__ void scan_block(const int* __restrict__ cnt, int* __restrict__ offs,
                           int* __restrict__ bsum, int n) {
    __shared__ int sm[256];
    int t = threadIdx.x;
    int i = blockIdx.x * 256 + t;
    int v = (i < n) ? cnt[i] : 0;
    sm[t] = v;
    __syncthreads();
#pragma unroll
    for (int d = 1; d < 256; d <<= 1) {
        int add = (t >= d) ? sm[t - d] : 0;
        __syncthreads();
        sm[t] += add;
        __syncthreads();
    }
    if (i < n) offs[i] = sm[t] - v;
    if (t == 255) bsum[blockIdx.x] = sm[t];
}

__global__ void scan_bsum_par(int* __restrict__ bsum, int nb) {
    __shared__ int sm[512];
    int t = threadIdx.x;
    if (nb <= 512) {
        int v = (t < nb) ? bsum[t] : 0;
        sm[t] = v;
        __syncthreads();
#pragma unroll
        for (int d = 1; d < 512; d <<= 1) {
            int add = (t >= d) ? sm[t - d] : 0;
            __syncthreads();
            sm[t] += add;
            __syncthreads();
        }
        if (t < nb) bsum[t] = sm[t] - v;
    } else if (t == 0) {
        int acc = 0;
        for (int i = 0; i < nb; ++i) { int v = bsum[i]; bsum[i] = acc; acc += v; }
    }
}

__global__ void scan_add(int* __restrict__ offs, int* __restrict__ fillc,
                         const int* __restrict__ bsum, int n, int E) {
    int i = blockIdx.x * 256 + threadIdx.x;
    if (i < n) {
        int v = offs[i] + bsum[blockIdx.x];
        offs[i]  = v;
        fillc[i] = v;
    }
    if (i == 0) offs[n] = E;
}

// --------------- single-pass fused attention + softmax + aggregation (fp8)
// One wave per dst node t; fp8 xl gathers (256 B/edge); lane-local per-head
// online (m,z) + defer-max; software-pipelined 4-edge groups.
__launch_bounds__(256)
__global__ void gat_aggregate(const int* __restrict__ offs, const int* __restrict__ sbuf,
                              const unsigned char* __restrict__ xl8,
                              const unsigned short* __restrict__ xr_,
                              const float* __restrict__ att,
                              float* __restrict__ out, int n) {
    const _Float16* xr = (const _Float16*)xr_;
    int lane = threadIdx.x & 63;
    int wid  = __builtin_amdgcn_readfirstlane((blockIdx.x * blockDim.x + threadIdx.x) >> 6);
    int nw   = (gridDim.x * blockDim.x) >> 6;

    const float LOG2E = 1.4426950408889634f;
    float4 af = *(const float4*)(att + lane * 4);   // flat[256]: lanes 0..31 head0
    float ax = af.x * LOG2E, ay = af.y * LOG2E, az = af.z * LOG2E, aw = af.w * LOG2E;

    for (int t = wid; t < n; t += nw) {
        int beg = offs[t];
        int end = offs[t + 1];
        if (beg == end) continue;
        h4 rr = *(const h4*)(xr + (size_t)t * 256 + lane * 4);
        float rx = (float)rr[0], ry = (float)rr[1], rz = (float)rr[2], rw = (float)rr[3];

        float m = -INFINITY, z = 0.f;
        float4 acc = make_float4(0.f, 0.f, 0.f, 0.f);

        auto process4 = [&](int u0, int u1, int u2, int u3) {
            f32x2 l0a = __builtin_amdgcn_cvt_pk_f32_fp8(u0, false);
            f32x2 l0b = __builtin_amdgcn_cvt_pk_f32_fp8(u0, true);
            f32x2 l1a = __builtin_amdgcn_cvt_pk_f32_fp8(u1, false);
            f32x2 l1b = __builtin_amdgcn_cvt_pk_f32_fp8(u1, true);
            f32x2 l2a = __builtin_amdgcn_cvt_pk_f32_fp8(u2, false);
            f32x2 l2b = __builtin_amdgcn_cvt_pk_f32_fp8(u2, true);
            f32x2 l3a = __builtin_amdgcn_cvt_pk_f32_fp8(u3, false);
            f32x2 l3b = __builtin_amdgcn_cvt_pk_f32_fp8(u3, true);

            auto logit = [&](f32x2 la, f32x2 lb) {
                float vx = la.x + rx; vx = fmaxf(vx, NEG_SLOPE * vx);
                float vy = la.y + ry; vy = fmaxf(vy, NEG_SLOPE * vy);
                float vz = lb.x + rz; vz = fmaxf(vz, NEG_SLOPE * vz);
                float vw = lb.y + rw; vw = fmaxf(vw, NEG_SLOPE * vw);
                return fmaf(vw, aw, fmaf(vz, az, fmaf(vy, ay, vx * ax)));
            };
            float p0 = halfsum(logit(l0a, l0b));
            float p1 = halfsum(logit(l1a, l1b));
            float p2 = halfsum(logit(l2a, l2b));
            float p3 = halfsum(logit(l3a, l3b));
            float pm = fmaxf(fmaxf(p0, p1), fmaxf(p2, p3));
            if (__any(pm - m > 11.5f)) {
                float mn = fmaxf(m, pm);
                float sc = __builtin_amdgcn_exp2f(m - mn);   // 0 on first group
                z *= sc;
                acc.x *= sc; acc.y *= sc; acc.z *= sc; acc.w *= sc;
                m = mn;
            }
            float w0 = __builtin_amdgcn_exp2f(p0 - m);
            float w1 = __builtin_amdgcn_exp2f(p1 - m);
            float w2 = __builtin_amdgcn_exp2f(p2 - m);
            float w3 = __builtin_amdgcn_exp2f(p3 - m);
            z += (w0 + w1) + (w2 + w3);
            acc.x = fmaf(l0a.x, w0, acc.x); acc.y = fmaf(l0a.y, w0, acc.y);
            acc.z = fmaf(l0b.x, w0, acc.z); acc.w = fmaf(l0b.y, w0, acc.w);
            acc.x = fmaf(l1a.x, w1, acc.x); acc.y = fmaf(l1a.y, w1, acc.y);
            acc.z = fmaf(l1b.x, w1, acc.z); acc.w = fmaf(l1b.y, w1, acc.w);
            acc.x = fmaf(l2a.x, w2, acc.x); acc.y = fmaf(l2a.y, w2, acc.y);
            acc.z = fmaf(l2b.x, w2, acc.z); acc.w = fmaf(l2b.y, w2, acc.w);
            acc.x = fmaf(l3a.x, w3, acc.x); acc.y = fmaf(l3a.y, w3, acc.y);
            acc.z = fmaf(l3b.x, w3, acc.z); acc.w = fmaf(l3b.y, w3, acc.w);
        };

        int j = beg;
        int c0, c1, c2, c3;
        bool have = (j + 4 <= end);
        if (have) {
            int s0 = sbuf[j], s1 = sbuf[j + 1], s2 = sbuf[j + 2], s3 = sbuf[j + 3];
            c0 = *(const int*)(xl8 + (size_t)s0 * 256 + lane * 4);
            c1 = *(const int*)(xl8 + (size_t)s1 * 256 + lane * 4);
            c2 = *(const int*)(xl8 + (size_t)s2 * 256 + lane * 4);
            c3 = *(const int*)(xl8 + (size_t)s3 * 256 + lane * 4);
        }
        for (; j + 8 <= end; j += 4) {
            int s0 = sbuf[j + 4], s1 = sbuf[j + 5], s2 = sbuf[j + 6], s3 = sbuf[j + 7];
            int n0 = *(const int*)(xl8 + (size_t)s0 * 256 + lane * 4);
            int n1 = *(const int*)(xl8 + (size_t)s1 * 256 + lane * 4);
            int n2 = *(const int*)(xl8 + (size_t)s2 * 256 + lane * 4);
            int n3 = *(const int*)(xl8 + (size_t)s3 * 256 + lane * 4);
            process4(c0, c1, c2, c3);
            c0 = n0; c1 = n1; c2 = n2; c3 = n3;
        }
        if (have) { process4(c0, c1, c2, c3); j += 4; }
        for (; j < end; ++j) {                   // tail (0..3 edges)
            int u = *(const int*)(xl8 + (size_t)sbuf[j] * 256 + lane * 4);
            f32x2 la = __builtin_amdgcn_cvt_pk_f32_fp8(u, false);
            f32x2 lb = __builtin_amdgcn_cvt_pk_f32_fp8(u, true);
            float vx = la.x + rx; vx = fmaxf(vx, NEG_SLOPE * vx);
            float vy = la.y + ry; vy = fmaxf(vy, NEG_SLOPE * vy);
            float vz = lb.x + rz; vz = fmaxf(vz, NEG_SLOPE * vz);
            float vw = lb.y + rw; vw = fmaxf(vw, NEG_SLOPE * vw);
            float p = halfsum(fmaf(vw, aw, fmaf(vz, az, fmaf(vy, ay, vx * ax))));
            if (__any(p - m > 11.5f)) {
                float mn = fmaxf(m, p);
                float sc = __builtin_amdgcn_exp2f(m - mn);
                z *= sc;
                acc.x *= sc; acc.y *= sc; acc.z *= sc; acc.w *= sc;
                m = mn;
            }
            float w = __builtin_amdgcn_exp2f(p - m);
            z += w;
            acc.x = fmaf(la.x, w, acc.x); acc.y = fmaf(la.y, w, acc.y);
            acc.z = fmaf(lb.x, w, acc.z); acc.w = fmaf(lb.y, w, acc.w);
        }
        float inv = 0.5f / (z + 1e-16f);         // z uniform within each half
        acc.x *= inv; acc.y *= inv; acc.z *= inv; acc.w *= inv;
        // head mean: lane L (<32) += lane L+32 (same channels, head 1)
        acc.x += __shfl_xor(acc.x, 32);
        acc.y += __shfl_xor(acc.y, 32);
        acc.z += __shfl_xor(acc.z, 32);
        acc.w += __shfl_xor(acc.w, 32);
        if (lane < 32) {
            float4* o = (float4*)(out + (size_t)t * DCH + lane * 4);
            float4 cur = *o;
            cur.x += acc.x; cur.y += acc.y; cur.z += acc.z; cur.w += acc.w;
            *o = cur;
        }
    }
}

// --------------------------------------------------------------------- launch
extern "C" void kernel_launch(void* const* d_in, const int* in_sizes, int n_in,
                              void* d_out, int out_size, void* d_ws, size_t ws_size,
                              hipStream_t stream) {
    const float* x     = (const float*)d_in[0];
    const int*   ei    = (const int*)d_in[1];
    const float* gamma = (const float*)d_in[2];
    const float* beta  = (const float*)d_in[3];
    const float* Wl    = (const float*)d_in[4];
    const float* bl    = (const float*)d_in[5];
    const float* Wr    = (const float*)d_in[6];
    const float* br    = (const float*)d_in[7];
    const float* att   = (const float*)d_in[8];
    const float* resW  = (const float*)d_in[9];
    const float* bias  = (const float*)d_in[10];
    float* out = (float*)d_out;

    int n = in_sizes[0] / DCH;
    int E = in_sizes[1] / 2;
    const int* src = ei;
    const int* dstIdx = ei + E;

    char* ws = (char*)d_ws;
    size_t off = 0;
    auto alloc = [&](size_t bytes) -> void* {
        void* p = ws + off;
        off = (off + bytes + 255) & ~(size_t)255;
        return p;
    };

    int nb = (n + 255) / 256;

    unsigned char*  xl8 = (unsigned char*)alloc((size_t)n * 256);       // 25.6 MB
    unsigned short* xr  = (unsigned short*)alloc((size_t)n * 256 * 2);  // 51.2 MB
    unsigned short* wfrag = (unsigned short*)alloc(160 * 64 * 8 * 2);   // 160 KB
    int* cnt   = (int*)alloc((size_t)n * 4);
    int* offs  = (int*)alloc((size_t)(n + 1) * 4);
    int* bsum  = (int*)alloc((size_t)nb * 4);
    int* fillc = (int*)alloc((size_t)n * 4);
    int* sbuf  = (int*)alloc((size_t)E * 4);                            // 6.4 MB

    (void)hipMemsetAsync(cnt, 0, (size_t)n * 4, stream);
    int ethr = (E / 4 + 255) / 256 + 1;
    prep_hist<<<40 + ethr, 256, 0, stream>>>(Wl, Wr, resW, wfrag, dstIdx, cnt, E);
    scan_block<<<nb, 256, 0, stream>>>(cnt, offs, bsum, n);
    scan_bsum_par<<<1, 512, 0, stream>>>(bsum, nb);
    scan_add<<<nb, 256, 0, stream>>>(offs, fillc, bsum, n, E);

    int nrb = (n + 127) / 128;
    gemm_fill<<<nrb + ethr, 256, 0, stream>>>(x, gamma, beta, wfrag, bl, br, bias,
                                              xl8, xr, out, n,
                                              src, dstIdx, fillc, sbuf, E, nrb);
    gat_aggregate<<<2048, 256, 0, stream>>>(offs, sbuf, xl8, xr, att, out, n);
}

// Round 17
// 286.489 us; speedup vs baseline: 1.1871x; 1.0262x over previous
//
#include <hip/hip_runtime.h>
#include <hip/hip_bf16.h>
#include <cstdint>
#include <cstddef>

#define DCH 128
#define NHEADS 2
#define NEG_SLOPE 0.2f

typedef __attribute__((ext_vector_type(8))) short short8v;
typedef __attribute__((ext_vector_type(4))) float f32x4;
typedef __attribute__((ext_vector_type(2))) float f32x2;
typedef __attribute__((ext_vector_type(4))) int int4v;
typedef _Float16 h4 __attribute__((ext_vector_type(4)));

// ---------------------------------------------------------------- utilities
__device__ __forceinline__ unsigned short f2bf(float f) {
    union { float f; unsigned int i; } v; v.f = f;
    unsigned int r = v.i + 0x7fffu + ((v.i >> 16) & 1u);   // RNE
    return (unsigned short)(r >> 16);
}
__device__ __forceinline__ unsigned short f2h_bits(float f) {
    _Float16 h = (_Float16)f;
    union { _Float16 h; unsigned short u; } v; v.h = h; return v.u;
}

// 32-lane-half sum via DPP row_ror + one ds_swizzle (xor16).
__device__ __forceinline__ float halfsum(float p) {
    p += __int_as_float(__builtin_amdgcn_update_dpp(
            0, __float_as_int(p), 0x121, 0xF, 0xF, false));  // row_ror:1
    p += __int_as_float(__builtin_amdgcn_update_dpp(
            0, __float_as_int(p), 0x122, 0xF, 0xF, false));  // row_ror:2
    p += __int_as_float(__builtin_amdgcn_update_dpp(
            0, __float_as_int(p), 0x124, 0xF, 0xF, false));  // row_ror:4
    p += __int_as_float(__builtin_amdgcn_update_dpp(
            0, __float_as_int(p), 0x128, 0xF, 0xF, false));  // row_ror:8
    p += __int_as_float(__builtin_amdgcn_ds_swizzle(
            __float_as_int(p), 0x401F));                     // lane ^= 16
    return p;
}

// ------------- merged: weights->bf16 fragments + dst histogram (cnt pre-zeroed
// by hipMemsetAsync). Blocks [0,40): wfrag; blocks >= 40: int4 histogram.
__global__ void prep_hist(const float* __restrict__ Wl, const float* __restrict__ Wr,
                          const float* __restrict__ resW,
                          unsigned short* __restrict__ wfrag,
                          const int* __restrict__ dst, int* __restrict__ cnt, int E) {
    if (blockIdx.x >= 40) {
        int i = (blockIdx.x - 40) * 256 + threadIdx.x;
        int E4 = E >> 2;
        if (i < E4) {
            int4 d = ((const int4*)dst)[i];
            atomicAdd(&cnt[d.x], 1); atomicAdd(&cnt[d.y], 1);
            atomicAdd(&cnt[d.z], 1); atomicAdd(&cnt[d.w], 1);
        }
        if (i < (E & 3)) atomicAdd(&cnt[dst[E4 * 4 + i]], 1);
        return;
    }
    int gid  = blockIdx.x * 256 + threadIdx.x;   // 10240 threads
    int lane = gid & 63;
    int f    = gid >> 6;                          // 0..159
    int ks   = f & 3;
    int ct   = f >> 2;
    int col  = ct * 16 + (lane & 15);
    int k0   = ks * 32 + (lane >> 4) * 8;
    const float* W; int ldB, c;
    if (col < 256)      { W = Wl;   ldB = 256; c = col; }
    else if (col < 512) { W = Wr;   ldB = 256; c = col - 256; }
    else                { W = resW; ldB = 128; c = col - 512; }
    unsigned short tmp[8];
#pragma unroll
    for (int j = 0; j < 8; ++j) tmp[j] = f2bf(W[(size_t)(k0 + j) * ldB + c]);
    ushort4* dstp = (ushort4*)(wfrag + (size_t)gid * 8);
    dstp[0] = make_ushort4(tmp[0], tmp[1], tmp[2], tmp[3]);
    dstp[1] = make_ushort4(tmp[4], tmp[5], tmp[6], tmp[7]);
}

// ------- combined dispatch: blocks [0,nrb) = LN+MFMA GEMM (128-row tiles),
// rest = fill_csr (int4, 4 edges/thread).
// GEMM outputs staged in 32KB LDS (aliases A tile), flushed full-line.
__launch_bounds__(256)
__global__ void gemm_fill(const float* __restrict__ x,
                          const float* __restrict__ gamma, const float* __restrict__ beta,
                          const unsigned short* __restrict__ wfrag,
                          const float* __restrict__ bl, const float* __restrict__ br,
                          const float* __restrict__ bias,
                          unsigned char* __restrict__ xl8, unsigned short* __restrict__ xr,
                          float* __restrict__ out, int n,
                          const int* __restrict__ srcIdx, const int* __restrict__ dstIdx,
                          int* __restrict__ fillc, int* __restrict__ sbuf, int E, int nrb) {
    __shared__ __align__(16) unsigned char smem[128 * 256];  // 32 KB (As / stage)

    if ((int)blockIdx.x >= nrb) {
        // ---------------- fill_csr part (4 edges per thread, int4 loads)
        int i = (blockIdx.x - nrb) * 256 + threadIdx.x;
        int E4 = E >> 2;
        if (i < E4) {
            int4 d = ((const int4*)dstIdx)[i];
            int4 s = ((const int4*)srcIdx)[i];
            sbuf[atomicAdd(&fillc[d.x], 1)] = s.x;
            sbuf[atomicAdd(&fillc[d.y], 1)] = s.y;
            sbuf[atomicAdd(&fillc[d.z], 1)] = s.z;
            sbuf[atomicAdd(&fillc[d.w], 1)] = s.w;
        }
        if (i < (E & 3)) {
            int e = E4 * 4 + i;
            sbuf[atomicAdd(&fillc[dstIdx[e]], 1)] = srcIdx[e];
        }
        return;
    }

    // ---------------- GEMM part (128 rows x 640 cols)
    int row0 = blockIdx.x * 128;
    int tid  = threadIdx.x;
    unsigned short* As = (unsigned short*)smem;

    // stage A with fused LayerNorm+ReLU (bf16, XOR-swizzled)
    {
        int r  = tid >> 5;            // 0..7
        int k4 = (tid & 31) * 4;      // 0,4,...,124
        float4 g4  = *(const float4*)(gamma + k4);
        float4 be4 = *(const float4*)(beta + k4);
#pragma unroll
        for (int i = 0; i < 16; ++i) {
            int row  = r + i * 8;
            int grow = row0 + row;
            float4 a = (grow < n) ? *(const float4*)(x + (size_t)grow * DCH + k4)
                                  : make_float4(0.f, 0.f, 0.f, 0.f);
            float s  = a.x + a.y + a.z + a.w;
            float sq = a.x * a.x + a.y * a.y + a.z * a.z + a.w * a.w;
#pragma unroll
            for (int msk = 16; msk; msk >>= 1) {
                s  += __shfl_xor(s, msk);
                sq += __shfl_xor(sq, msk);
            }
            float mu = s * (1.f / DCH);
            float rs = rsqrtf(sq * (1.f / DCH) - mu * mu + 1e-5f);
            ushort4 u;
            u.x = f2bf(fmaxf((a.x - mu) * rs * g4.x + be4.x, 0.f));
            u.y = f2bf(fmaxf((a.y - mu) * rs * g4.y + be4.y, 0.f));
            u.z = f2bf(fmaxf((a.z - mu) * rs * g4.z + be4.z, 0.f));
            u.w = f2bf(fmaxf((a.w - mu) * rs * g4.w + be4.w, 0.f));
            int byteoff = row * 256 + ((k4 * 2) ^ ((row & 7) << 4));
            *(ushort4*)((char*)As + byteoff) = u;
        }
    }
    __syncthreads();

    int wv = tid >> 6, lane = tid & 63;

    short8v afrag[2][4];
#pragma unroll
    for (int g = 0; g < 2; ++g) {
        int arow = wv * 32 + g * 16 + (lane & 15);
#pragma unroll
        for (int ks = 0; ks < 4; ++ks) {
            int kbyte = (ks * 64 + (lane >> 4) * 16) ^ ((arow & 7) << 4);
            afrag[g][ks] = *(const short8v*)((const char*)As + arow * 256 + kbyte);
        }
    }
    __syncthreads();   // fragment reads done; smem becomes the stage buffer

    int nodeL0 = wv * 32 + (lane & 15);      // local node, group 0 (0..127)
    int nodeL1 = nodeL0 + 16;                // group 1
    int cq = (lane >> 4) << 2;               // column quad 0,4,8,12

    auto mfma_ct = [&](int ct, f32x4& a0, f32x4& a1) {
        const unsigned short* bp = wfrag + ((size_t)(ct * 4) * 64 + lane) * 8;
        short8v b0 = *(const short8v*)(bp);
        short8v b1 = *(const short8v*)(bp + 64 * 8);
        short8v b2 = *(const short8v*)(bp + 128 * 8);
        short8v b3 = *(const short8v*)(bp + 192 * 8);
        a0 = __builtin_amdgcn_mfma_f32_16x16x32_bf16(b0, afrag[0][0], a0, 0, 0, 0);
        a1 = __builtin_amdgcn_mfma_f32_16x16x32_bf16(b0, afrag[1][0], a1, 0, 0, 0);
        a0 = __builtin_amdgcn_mfma_f32_16x16x32_bf16(b1, afrag[0][1], a0, 0, 0, 0);
        a1 = __builtin_amdgcn_mfma_f32_16x16x32_bf16(b1, afrag[1][1], a1, 0, 0, 0);
        a0 = __builtin_amdgcn_mfma_f32_16x16x32_bf16(b2, afrag[0][2], a0, 0, 0, 0);
        a1 = __builtin_amdgcn_mfma_f32_16x16x32_bf16(b2, afrag[1][2], a1, 0, 0, 0);
        a0 = __builtin_amdgcn_mfma_f32_16x16x32_bf16(b3, afrag[0][3], a0, 0, 0, 0);
        a1 = __builtin_amdgcn_mfma_f32_16x16x32_bf16(b3, afrag[1][3], a1, 0, 0, 0);
    };

    // ---- xl (fp8): 16 cts; stage = [128 nodes][256 B]; NORMAL stores
    {
#pragma unroll
        for (int ct = 0; ct < 16; ++ct) {
            f32x4 a0 = {0,0,0,0}, a1 = {0,0,0,0};
            mfma_ct(ct, a0, a1);
            int c = ct * 16 + cq;
            float4 bb = *(const float4*)(bl + c);
            int cb = ct * 16 + cq;                       // byte in [0,256)
            int p0 = __builtin_amdgcn_cvt_pk_fp8_f32(a0[0] + bb.x, a0[1] + bb.y, 0, false);
            p0     = __builtin_amdgcn_cvt_pk_fp8_f32(a0[2] + bb.z, a0[3] + bb.w, p0, true);
            *(int*)(smem + nodeL0 * 256 + (cb ^ ((nodeL0 & 7) << 4))) = p0;
            int p1 = __builtin_amdgcn_cvt_pk_fp8_f32(a1[0] + bb.x, a1[1] + bb.y, 0, false);
            p1     = __builtin_amdgcn_cvt_pk_fp8_f32(a1[2] + bb.z, a1[3] + bb.w, p1, true);
            *(int*)(smem + nodeL1 * 256 + (cb ^ ((nodeL1 & 7) << 4))) = p1;
        }
        __syncthreads();
#pragma unroll
        for (int it = 0; it < 8; ++it) {        // flush 32KB, full-line stores
            int chunk = it * 256 + tid;
            int row  = chunk >> 4;
            int colb = (chunk & 15) * 16;
            int grow = row0 + row;
            if (grow < n) {
                int4v v = *(const int4v*)(smem + row * 256 + (colb ^ ((row & 7) << 4)));
                *(int4v*)(xl8 + (size_t)grow * 256 + colb) = v;
            }
        }
        __syncthreads();
    }

    // ---- xr (f16): 2 flush-groups of 8 cts; NONTEMPORAL flush
    for (int fg = 0; fg < 2; ++fg) {
#pragma unroll
        for (int ctl = 0; ctl < 8; ++ctl) {
            int ct = 16 + fg * 8 + ctl;
            f32x4 a0 = {0,0,0,0}, a1 = {0,0,0,0};
            mfma_ct(ct, a0, a1);
            int c = ct * 16 + cq - 256;                  // col in [0,256)
            float4 bb = *(const float4*)(br + c);
            int cb = ctl * 32 + cq * 2;                  // byte in [0,256)
            ushort4 u0 = make_ushort4(f2h_bits(a0[0] + bb.x), f2h_bits(a0[1] + bb.y),
                                      f2h_bits(a0[2] + bb.z), f2h_bits(a0[3] + bb.w));
            *(ushort4*)(smem + nodeL0 * 256 + (cb ^ ((nodeL0 & 7) << 4))) = u0;
            ushort4 u1 = make_ushort4(f2h_bits(a1[0] + bb.x), f2h_bits(a1[1] + bb.y),
                                      f2h_bits(a1[2] + bb.z), f2h_bits(a1[3] + bb.w));
            *(ushort4*)(smem + nodeL1 * 256 + (cb ^ ((nodeL1 & 7) << 4))) = u1;
        }
        __syncthreads();
#pragma unroll
        for (int it = 0; it < 8; ++it) {
            int chunk = it * 256 + tid;
            int row  = chunk >> 4;
            int colb = (chunk & 15) * 16;
            int grow = row0 + row;
            if (grow < n) {
                int4v v = *(const int4v*)(smem + row * 256 + (colb ^ ((row & 7) << 4)));
                __builtin_nontemporal_store(v,
                    (int4v*)((char*)xr + (size_t)grow * 512 + fg * 256 + colb));
            }
        }
        __syncthreads();
    }

    // ---- out: 2 flush-groups of 4 cts; NONTEMPORAL flush + residual x
    for (int fg = 0; fg < 2; ++fg) {
#pragma unroll
        for (int ctl = 0; ctl < 4; ++ctl) {
            int ct = 32 + fg * 4 + ctl;
            f32x4 a0 = {0,0,0,0}, a1 = {0,0,0,0};
            mfma_ct(ct, a0, a1);
            int c = ct * 16 + cq - 512;                  // col in [0,128)
            float4 bb = *(const float4*)(bias + c);
            int cb = ctl * 64 + cq * 4;                  // byte in [0,256)
            float4 w0 = make_float4(a0[0] + bb.x, a0[1] + bb.y,
                                    a0[2] + bb.z, a0[3] + bb.w);
            *(float4*)(smem + nodeL0 * 256 + (cb ^ ((nodeL0 & 7) << 4))) = w0;
            float4 w1 = make_float4(a1[0] + bb.x, a1[1] + bb.y,
                                    a1[2] + bb.z, a1[3] + bb.w);
            *(float4*)(smem + nodeL1 * 256 + (cb ^ ((nodeL1 & 7) << 4))) = w1;
        }
        __syncthreads();
#pragma unroll
        for (int it = 0; it < 8; ++it) {
            int chunk = it * 256 + tid;
            int row  = chunk >> 4;
            int colb = (chunk & 15) * 16;
            int grow = row0 + row;
            if (grow < n) {
                f32x4 v = *(const f32x4*)(smem + row * 256 + (colb ^ ((row & 7) << 4)));
                const float* xp = (const float*)((const char*)x + (size_t)grow * 512 + fg * 256 + colb);
                f32x4 xv = *(const f32x4*)xp;
                v = v + xv;
                __builtin_nontemporal_store(v,
                    (f32x4*)((char*)out + (size_t)grow * 512 + fg * 256 + colb));
            }
        }
        __syncthreads();
    }
}

// --------------------------------------------------------------- CSR scans
__global__ void scan_block(const int* __restrict__ cnt, int* __restrict__ offs,
                           int* __restrict__ bsum, int n) {
    __shared__ int sm[256];
    int t = threadIdx.x;
    int i = blockIdx.x * 256 + t;
    int v = (i < n) ? cnt[i] : 0;
    sm[t] = v;
    __syncthreads();
#pragma unroll
    for (int d = 1; d < 256; d <<= 1) {
        int add = (t >= d) ? sm[t - d] : 0;
        __syncthreads();
        sm[t] += add;
        __syncthreads();
    }
    if (i < n) offs[i] = sm[t] - v;
    if (t == 255) bsum[blockIdx.x] = sm[t];
}

__global__ void scan_bsum_par(int* __restrict__ bsum, int nb) {
    __shared__ int sm[512];
    int t = threadIdx.x;
    if (nb <= 512) {
        int v = (t < nb) ? bsum[t] : 0;
        sm[t] = v;
        __syncthreads();
#pragma unroll
        for (int d = 1; d < 512; d <<= 1) {
            int add = (t >= d) ? sm[t - d] : 0;
            __syncthreads();
            sm[t] += add;
            __syncthreads();
        }
        if (t < nb) bsum[t] = sm[t] - v;
    } else if (t == 0) {
        int acc = 0;
        for (int i = 0; i < nb; ++i) { int v = bsum[i]; bsum[i] = acc; acc += v; }
    }
}

__global__ void scan_add(int* __restrict__ offs, int* __restrict__ fillc,
                         const int* __restrict__ bsum, int n, int E) {
    int i = blockIdx.x * 256 + threadIdx.x;
    if (i < n) {
        int v = offs[i] + bsum[blockIdx.x];
        offs[i]  = v;
        fillc[i] = v;
    }
    if (i == 0) offs[n] = E;
}

// --------------- single-pass fused attention + softmax + aggregation (fp8)
// One wave per dst node t; fp8 xl gathers (256 B/edge); lane-local per-head
// online (m,z) + defer-max; 8-edge (2-group) deep gather pipeline.
__launch_bounds__(256)
__global__ void gat_aggregate(const int* __restrict__ offs, const int* __restrict__ sbuf,
                              const unsigned char* __restrict__ xl8,
                              const unsigned short* __restrict__ xr_,
                              const float* __restrict__ att,
                              float* __restrict__ out, int n) {
    const _Float16* xr = (const _Float16*)xr_;
    int lane = threadIdx.x & 63;
    int wid  = __builtin_amdgcn_readfirstlane((blockIdx.x * blockDim.x + threadIdx.x) >> 6);
    int nw   = (gridDim.x * blockDim.x) >> 6;

    const float LOG2E = 1.4426950408889634f;
    float4 af = *(const float4*)(att + lane * 4);   // flat[256]: lanes 0..31 head0
    float ax = af.x * LOG2E, ay = af.y * LOG2E, az = af.z * LOG2E, aw = af.w * LOG2E;

    for (int t = wid; t < n; t += nw) {
        int beg = offs[t];
        int end = offs[t + 1];
        if (beg == end) continue;
        h4 rr = *(const h4*)(xr + (size_t)t * 256 + lane * 4);
        float rx = (float)rr[0], ry = (float)rr[1], rz = (float)rr[2], rw = (float)rr[3];

        float m = -INFINITY, z = 0.f;
        float4 acc = make_float4(0.f, 0.f, 0.f, 0.f);

        auto process4 = [&](int u0, int u1, int u2, int u3) {
            f32x2 l0a = __builtin_amdgcn_cvt_pk_f32_fp8(u0, false);
            f32x2 l0b = __builtin_amdgcn_cvt_pk_f32_fp8(u0, true);
            f32x2 l1a = __builtin_amdgcn_cvt_pk_f32_fp8(u1, false);
            f32x2 l1b = __builtin_amdgcn_cvt_pk_f32_fp8(u1, true);
            f32x2 l2a = __builtin_amdgcn_cvt_pk_f32_fp8(u2, false);
            f32x2 l2b = __builtin_amdgcn_cvt_pk_f32_fp8(u2, true);
            f32x2 l3a = __builtin_amdgcn_cvt_pk_f32_fp8(u3, false);
            f32x2 l3b = __builtin_amdgcn_cvt_pk_f32_fp8(u3, true);

            auto logit = [&](f32x2 la, f32x2 lb) {
                float vx = la.x + rx; vx = fmaxf(vx, NEG_SLOPE * vx);
                float vy = la.y + ry; vy = fmaxf(vy, NEG_SLOPE * vy);
                float vz = lb.x + rz; vz = fmaxf(vz, NEG_SLOPE * vz);
                float vw = lb.y + rw; vw = fmaxf(vw, NEG_SLOPE * vw);
                return fmaf(vw, aw, fmaf(vz, az, fmaf(vy, ay, vx * ax)));
            };
            float p0 = halfsum(logit(l0a, l0b));
            float p1 = halfsum(logit(l1a, l1b));
            float p2 = halfsum(logit(l2a, l2b));
            float p3 = halfsum(logit(l3a, l3b));
            float pm = fmaxf(fmaxf(p0, p1), fmaxf(p2, p3));
            if (__any(pm - m > 11.5f)) {
                float mn = fmaxf(m, pm);
                float sc = __builtin_amdgcn_exp2f(m - mn);   // 0 on first group
                z *= sc;
                acc.x *= sc; acc.y *= sc; acc.z *= sc; acc.w *= sc;
                m = mn;
            }
            float w0 = __builtin_amdgcn_exp2f(p0 - m);
            float w1 = __builtin_amdgcn_exp2f(p1 - m);
            float w2 = __builtin_amdgcn_exp2f(p2 - m);
            float w3 = __builtin_amdgcn_exp2f(p3 - m);
            z += (w0 + w1) + (w2 + w3);
            acc.x = fmaf(l0a.x, w0, acc.x); acc.y = fmaf(l0a.y, w0, acc.y);
            acc.z = fmaf(l0b.x, w0, acc.z); acc.w = fmaf(l0b.y, w0, acc.w);
            acc.x = fmaf(l1a.x, w1, acc.x); acc.y = fmaf(l1a.y, w1, acc.y);
            acc.z = fmaf(l1b.x, w1, acc.z); acc.w = fmaf(l1b.y, w1, acc.w);
            acc.x = fmaf(l2a.x, w2, acc.x); acc.y = fmaf(l2a.y, w2, acc.y);
            acc.z = fmaf(l2b.x, w2, acc.z); acc.w = fmaf(l2b.y, w2, acc.w);
            acc.x = fmaf(l3a.x, w3, acc.x); acc.y = fmaf(l3a.y, w3, acc.y);
            acc.z = fmaf(l3b.x, w3, acc.z); acc.w = fmaf(l3b.y, w3, acc.w);
        };

        int j = beg;
        int c0, c1, c2, c3;      // group in flight (oldest)
        int d0, d1, d2, d3;      // second group in flight
        bool haveC = (j + 4 <= end);
        if (haveC) {
            int s0 = sbuf[j], s1 = sbuf[j + 1], s2 = sbuf[j + 2], s3 = sbuf[j + 3];
            c0 = *(const int*)(xl8 + (size_t)s0 * 256 + lane * 4);
            c1 = *(const int*)(xl8 + (size_t)s1 * 256 + lane * 4);
            c2 = *(const int*)(xl8 + (size_t)s2 * 256 + lane * 4);
            c3 = *(const int*)(xl8 + (size_t)s3 * 256 + lane * 4);
        }
        bool haveD = (j + 8 <= end);
        if (haveD) {
            int s0 = sbuf[j + 4], s1 = sbuf[j + 5], s2 = sbuf[j + 6], s3 = sbuf[j + 7];
            d0 = *(const int*)(xl8 + (size_t)s0 * 256 + lane * 4);
            d1 = *(const int*)(xl8 + (size_t)s1 * 256 + lane * 4);
            d2 = *(const int*)(xl8 + (size_t)s2 * 256 + lane * 4);
            d3 = *(const int*)(xl8 + (size_t)s3 * 256 + lane * 4);
        }
        for (; j + 12 <= end; j += 4) {
            // prefetch group j+8 while processing group j (2 groups in flight)
            int s0 = sbuf[j + 8], s1 = sbuf[j + 9], s2 = sbuf[j + 10], s3 = sbuf[j + 11];
            int n0 = *(const int*)(xl8 + (size_t)s0 * 256 + lane * 4);
            int n1 = *(const int*)(xl8 + (size_t)s1 * 256 + lane * 4);
            int n2 = *(const int*)(xl8 + (size_t)s2 * 256 + lane * 4);
            int n3 = *(const int*)(xl8 + (size_t)s3 * 256 + lane * 4);
            process4(c0, c1, c2, c3);
            c0 = d0; c1 = d1; c2 = d2; c3 = d3;
            d0 = n0; d1 = n1; d2 = n2; d3 = n3;
        }
        if (haveD) {                 // two groups remain (c, d)
            process4(c0, c1, c2, c3);
            c0 = d0; c1 = d1; c2 = d2; c3 = d3;
            j += 4;
        }
        if (haveC) {                 // one group remains (c)
            process4(c0, c1, c2, c3);
            j += 4;
        }
        for (; j < end; ++j) {                   // tail (0..3 edges)
            int u = *(const int*)(xl8 + (size_t)sbuf[j] * 256 + lane * 4);
            f32x2 la = __builtin_amdgcn_cvt_pk_f32_fp8(u, false);
            f32x2 lb = __builtin_amdgcn_cvt_pk_f32_fp8(u, true);
            float vx = la.x + rx; vx = fmaxf(vx, NEG_SLOPE * vx);
            float vy = la.y + ry; vy = fmaxf(vy, NEG_SLOPE * vy);
            float vz = lb.x + rz; vz = fmaxf(vz, NEG_SLOPE * vz);
            float vw = lb.y + rw; vw = fmaxf(vw, NEG_SLOPE * vw);
            float p = halfsum(fmaf(vw, aw, fmaf(vz, az, fmaf(vy, ay, vx * ax))));
            if (__any(p - m > 11.5f)) {
                float mn = fmaxf(m, p);
                float sc = __builtin_amdgcn_exp2f(m - mn);
                z *= sc;
                acc.x *= sc; acc.y *= sc; acc.z *= sc; acc.w *= sc;
                m = mn;
            }
            float w = __builtin_amdgcn_exp2f(p - m);
            z += w;
            acc.x = fmaf(la.x, w, acc.x); acc.y = fmaf(la.y, w, acc.y);
            acc.z = fmaf(lb.x, w, acc.z); acc.w = fmaf(lb.y, w, acc.w);
        }
        float inv = 0.5f / (z + 1e-16f);         // z uniform within each half
        acc.x *= inv; acc.y *= inv; acc.z *= inv; acc.w *= inv;
        // head mean: lane L (<32) += lane L+32 (same channels, head 1)
        acc.x += __shfl_xor(acc.x, 32);
        acc.y += __shfl_xor(acc.y, 32);
        acc.z += __shfl_xor(acc.z, 32);
        acc.w += __shfl_xor(acc.w, 32);
        if (lane < 32) {
            float4* o = (float4*)(out + (size_t)t * DCH + lane * 4);
            float4 cur = *o;
            cur.x += acc.x; cur.y += acc.y; cur.z += acc.z; cur.w += acc.w;
            *o = cur;
        }
    }
}

// --------------------------------------------------------------------- launch
extern "C" void kernel_launch(void* const* d_in, const int* in_sizes, int n_in,
                              void* d_out, int out_size, void* d_ws, size_t ws_size,
                              hipStream_t stream) {
    const float* x     = (const float*)d_in[0];
    const int*   ei    = (const int*)d_in[1];
    const float* gamma = (const float*)d_in[2];
    const float* beta  = (const float*)d_in[3];
    const float* Wl    = (const float*)d_in[4];
    const float* bl    = (const float*)d_in[5];
    const float* Wr    = (const float*)d_in[6];
    const float* br    = (const float*)d_in[7];
    const float* att   = (const float*)d_in[8];
    const float* resW  = (const float*)d_in[9];
    const float* bias  = (const float*)d_in[10];
    float* out = (float*)d_out;

    int n = in_sizes[0] / DCH;
    int E = in_sizes[1] / 2;
    const int* src = ei;
    const int* dstIdx = ei + E;

    char* ws = (char*)d_ws;
    size_t off = 0;
    auto alloc = [&](size_t bytes) -> void* {
        void* p = ws + off;
        off = (off + bytes + 255) & ~(size_t)255;
        return p;
    };

    int nb = (n + 255) / 256;

    unsigned char*  xl8 = (unsigned char*)alloc((size_t)n * 256);       // 25.6 MB
    unsigned short* xr  = (unsigned short*)alloc((size_t)n * 256 * 2);  // 51.2 MB
    unsigned short* wfrag = (unsigned short*)alloc(160 * 64 * 8 * 2);   // 160 KB
    int* cnt   = (int*)alloc((size_t)n * 4);
    int* offs  = (int*)alloc((size_t)(n + 1) * 4);
    int* bsum  = (int*)alloc((size_t)nb * 4);
    int* fillc = (int*)alloc((size_t)n * 4);
    int* sbuf  = (int*)alloc((size_t)E * 4);                            // 6.4 MB

    (void)hipMemsetAsync(cnt, 0, (size_t)n * 4, stream);
    int ethr = (E / 4 + 255) / 256 + 1;
    prep_hist<<<40 + ethr, 256, 0, stream>>>(Wl, Wr, resW, wfrag, dstIdx, cnt, E);
    scan_block<<<nb, 256, 0, stream>>>(cnt, offs, bsum, n);
    scan_bsum_par<<<1, 512, 0, stream>>>(bsum, nb);
    scan_add<<<nb, 256, 0, stream>>>(offs, fillc, bsum, n, E);

    int nrb = (n + 127) / 128;
    gemm_fill<<<nrb + ethr, 256, 0, stream>>>(x, gamma, beta, wfrag, bl, br, bias,
                                              xl8, xr, out, n,
                                              src, dstIdx, fillc, sbuf, E, nrb);
    gat_aggregate<<<2048, 256, 0, stream>>>(offs, sbuf, xl8, xr, att, out, n);
}